// Round 8
// baseline (181.088 us; speedup 1.0000x reference)
//
#include <hip/hip_runtime.h>

#define S_LEN 2048
#define EDIM  1024
#define HEADS 16
#define DHEAD 64

typedef __attribute__((ext_vector_type(8))) short bf16x8;
typedef __attribute__((ext_vector_type(4))) short short4v;
typedef __attribute__((ext_vector_type(4))) float f32x4;

__device__ inline unsigned short f2bf(float f) {
    unsigned int u = __float_as_uint(f);
    unsigned int r = (u + 0x7FFFu + ((u >> 16) & 1u)) >> 16;
    return (unsigned short)r;
}
__device__ inline float bf2f(unsigned short b) {
    return __uint_as_float(((unsigned int)b) << 16);
}
__device__ inline void load_lds16(const void* g, void* l) {
    __builtin_amdgcn_global_load_lds(
        (const __attribute__((address_space(1))) unsigned int*)g,
        (__attribute__((address_space(3))) unsigned int*)l, 16, 0, 0);
}

// ---------------- X fp32 -> bf16 ----------------
__global__ void k_convert_x(const float* __restrict__ x, short* __restrict__ xb, int n4) {
    int i = blockIdx.x * blockDim.x + threadIdx.x;
    if (i >= n4) return;
    f32x4 v = ((const f32x4*)x)[i];
    short4v o;
    o[0] = (short)f2bf(v[0]); o[1] = (short)f2bf(v[1]);
    o[2] = (short)f2bf(v[2]); o[3] = (short)f2bf(v[3]);
    ((short4v*)xb)[i] = o;
}

// ---------------- tiled transpose + fp32->bf16: in[R][C] -> out[C][R], batched over z ----------------
__global__ void k_transpose_cvt(const float* __restrict__ in, short* __restrict__ out, int R, int C) {
    __shared__ float tile[32][33];
    const int b = blockIdx.z;
    in  += (size_t)b * R * C;
    out += (size_t)b * R * C;
    const int c0 = blockIdx.x * 32, r0 = blockIdx.y * 32;
    #pragma unroll
    for (int yy = 0; yy < 4; ++yy) {
        int r = r0 + threadIdx.y + yy * 8, c = c0 + threadIdx.x;
        tile[threadIdx.y + yy * 8][threadIdx.x] = (r < R && c < C) ? in[(size_t)r * C + c] : 0.f;
    }
    __syncthreads();
    #pragma unroll
    for (int yy = 0; yy < 4; ++yy) {
        int c = c0 + threadIdx.y + yy * 8, r = r0 + threadIdx.x;
        if (c < C && r < R) out[(size_t)c * R + r] = (short)f2bf(tile[threadIdx.x][threadIdx.y + yy * 8]);
    }
}

// ---------------- LDS-staged MFMA GEMM core (m97 structure) ----------------
template<int BM, int BN, int WR, int WC>
__device__ inline void gemm_core(const char* Ag, int ldaB, const char* Bg, int ldbB,
                                 int K, char* sA, char* sB, f32x4* acc) {
    constexpr int FM = BM / (WR * 16), FN = BN / (WC * 16);
    constexpr int RA = BM / 32, RB = BN / 32;
    const int lane = threadIdx.x & 63, wave = threadIdx.x >> 6;
    const int rl = lane & 15, g = lane >> 4;
    const int wrow = (wave / WC) * (BM / WR);
    const int wcol = (wave % WC) * (BN / WC);
    const int lr = lane >> 3;                 // row within 8-row staging group
    const int lc = ((lane & 7) ^ lr) << 4;    // inverse-swizzled 16B chunk
    const char* aSrc = Ag + (size_t)(wave * 8 + lr) * ldaB + lc;
    const char* bSrc = Bg + (size_t)(wave * 8 + lr) * ldbB + lc;

    for (int t = 0; t < K / 64; ++t) {
        __syncthreads();
        #pragma unroll
        for (int i = 0; i < RA; ++i)
            load_lds16(aSrc + (size_t)t * 128 + (size_t)i * 32 * ldaB, sA + (i * 4 + wave) * 1024);
        #pragma unroll
        for (int i = 0; i < RB; ++i)
            load_lds16(bSrc + (size_t)t * 128 + (size_t)i * 32 * ldbB, sB + (i * 4 + wave) * 1024);
        __syncthreads();
        #pragma unroll
        for (int kk = 0; kk < 2; ++kk) {
            bf16x8 af[FM], bf[FN];
            #pragma unroll
            for (int f = 0; f < FM; ++f) {
                const int r = wrow + f * 16 + rl;
                af[f] = *(const bf16x8*)(sA + r * 128 + (((kk * 4 + g) ^ (r & 7)) << 4));
            }
            #pragma unroll
            for (int j = 0; j < FN; ++j) {
                const int r = wcol + j * 16 + rl;
                bf[j] = *(const bf16x8*)(sB + r * 128 + (((kk * 4 + g) ^ (r & 7)) << 4));
            }
            #pragma unroll
            for (int f = 0; f < FM; ++f)
                #pragma unroll
                for (int j = 0; j < FN; ++j)
                    acc[f * FN + j] = __builtin_amdgcn_mfma_f32_16x16x32_bf16(af[f], bf[j], acc[f * FN + j], 0, 0, 0);
        }
    }
}

// ---------------- QKV projection GEMM (128x128 tiles, LDS-staged) ----------------
__global__ __launch_bounds__(256) void k_gemm_qkv(
        const short* __restrict__ Xb,
        const short* __restrict__ WqT, const short* __restrict__ WkT, const short* __restrict__ WvT,
        const float* __restrict__ bq, const float* __restrict__ bk, const float* __restrict__ bv,
        short* __restrict__ Qh, short* __restrict__ Kh, short* __restrict__ Vt) {
    __shared__ __align__(16) char sA[16384], sB[16384];
    int id = blockIdx.x;
    id = (id & 7) * 80 + (id >> 3);           // XCD-contiguous chunks
    const int mbase = (id % 16) * 128;
    const int y = id / 16;

    const short* Bt; const float* bias; int nbase; int which;
    if (y < 16)      { which = 0; Bt = WqT; bias = bq; nbase = y * 128; }
    else if (y < 32) { which = 1; Bt = WkT; bias = bk; nbase = (y - 16) * 128; }
    else             { which = 2; Bt = WvT; bias = bv; nbase = (y - 32) * 128; }

    f32x4 acc[16];
    #pragma unroll
    for (int i = 0; i < 16; ++i) acc[i] = (f32x4){0.f, 0.f, 0.f, 0.f};

    gemm_core<128, 128, 2, 2>((const char*)Xb + (size_t)mbase * 2048, 2048,
                              (const char*)Bt + (size_t)nbase * 2048, 2048,
                              EDIM, sA, sB, acc);

    const int lane = threadIdx.x & 63, wave = threadIdx.x >> 6;
    const int wr = (wave >> 1) * 64, wc = (wave & 1) * 64;
    const int rl = lane & 15, g = lane >> 4;
    const float qscale = 0.125f * 1.44269504088896f;
    #pragma unroll
    for (int i = 0; i < 4; ++i)
        #pragma unroll
        for (int j = 0; j < 4; ++j)
            #pragma unroll
            for (int jj = 0; jj < 4; ++jj) {
                int s = mbase + wr + i * 16 + g * 4 + jj;
                int n = nbase + wc + j * 16 + rl;
                float v = acc[i * 4 + j][jj] + bias[n];
                if (which == 0) v *= qscale;
                short b16 = (short)f2bf(v);
                if (which == 0)      Qh[((size_t)(n >> 7) * S_LEN + s) * 128 + (n & 127)] = b16;
                else if (which == 1) Kh[((size_t)(n >> 7) * S_LEN + s) * 128 + (n & 127)] = b16;
                else                 Vt[(size_t)n * S_LEN + s] = b16;
            }
}

// ---------------- differential flash attention, v6: shared-KV 8-wave + dbuf ----------------
// grid (S/128, H), 512 threads. All 8 waves own different 16 q-rows (128-row
// q-tile) and sweep the SAME KV range. K(16KB)+V(8KB) double-buffered (issue
// STAGE(next) before compute, one barrier/iter -> HBM latency hidden under
// QK/softmax/PV). P = 2KB/wave. LDS = 2x24KB + 16KB = 64KB.
__global__ __launch_bounds__(512, 2) void k_attn(
        const short* __restrict__ Qh, const short* __restrict__ Kh,
        const short* __restrict__ Vt, const float* __restrict__ lam_p,
        short* __restrict__ Ocat) {
    __shared__ __align__(16) char smem[65536];

    const int lane = threadIdx.x & 63, wave = threadIdx.x >> 6;
    const int rl = lane & 15, g = lane >> 4;
    const int h = blockIdx.y;
    const int qbase = blockIdx.x * 128 + wave * 16;
    const int swz = (rl & 7) << 4;
    const int kx = rl & 7;

    char* Pw = smem + 49152 + wave * 2048;    // [16][128B] per-wave P buffer

    const char* Kgb = (const char*)(Kh + (size_t)h * S_LEN * 128);
    const char* Vgb = (const char*)(Vt + (size_t)h * DHEAD * S_LEN);
    const short* Qp = Qh + (size_t)h * S_LEN * 128;

    // per-lane inverse-swizzled staging source offsets
    const int kofs0 = (lane >> 4) * 256 + (((lane & 15) ^ (lane >> 4)) << 4);
    const int kofs1 = (lane >> 4) * 256 + (((lane & 15) ^ ((lane >> 4) + 4)) << 4);
    const int vofs  = (lane >> 3) * 4096 + (((lane & 7) ^ (lane >> 3)) << 4);

    // stage kv-tile `it` into buffer b: each wave 2 K-chunks + 1 V-chunk
    auto STAGE = [&](int b, int it) {
        const size_t kv0 = (size_t)it * 64;
        char* kb = smem + b * 16384;
        char* vb = smem + 32768 + b * 8192;
        #pragma unroll
        for (int cc = 0; cc < 2; ++cc) {
            int c = wave * 2 + cc;
            load_lds16(Kgb + kv0 * 256 + c * 1024 + ((c & 1) ? kofs1 : kofs0), kb + c * 1024);
        }
        load_lds16(Vgb + (size_t)wave * 32768 + kv0 * 2 + vofs, vb + wave * 1024);
    };

    STAGE(0, 0);

    bf16x8 qf[2][2];
    #pragma unroll
    for (int p = 0; p < 2; ++p)
        #pragma unroll
        for (int kc = 0; kc < 2; ++kc)
            qf[p][kc] = *(const bf16x8*)&Qp[(size_t)(qbase + rl) * 128 + p * 64 + kc * 32 + g * 8];

    f32x4 acc[2][4];
    float m[2], l[2];
    #pragma unroll
    for (int p = 0; p < 2; ++p) {
        #pragma unroll
        for (int t = 0; t < 4; ++t) acc[p][t] = (f32x4){0.f, 0.f, 0.f, 0.f};
        m[p] = 0.f; l[p] = 0.f;
    }

    __syncthreads();   // prologue stage drained (vmcnt0 implied)

    const int NIT = S_LEN / 64;
    for (int it = 0; it < NIT; ++it) {
        const int cur = it & 1;
        if (it + 1 < NIT) STAGE(cur ^ 1, it + 1);   // issue-early prefetch
        const char* Kl = smem + cur * 16384;
        const char* Vl = smem + 32768 + cur * 8192;

        #pragma unroll
        for (int p = 0; p < 2; ++p) {
            // ---- QK^T (swapped: mfma(K,Q)); Q pre-scaled -> exp2 domain ----
            f32x4 sc[4];
            #pragma unroll
            for (int t = 0; t < 4; ++t) {
                f32x4 z = (f32x4){0.f, 0.f, 0.f, 0.f};
                #pragma unroll
                for (int kc = 0; kc < 2; ++kc) {
                    bf16x8 kf = *(const bf16x8*)(Kl + t * 4096 + rl * 256 + (((p * 8 + kc * 4 + g) ^ kx) << 4));
                    z = __builtin_amdgcn_mfma_f32_16x16x32_bf16(kf, qf[p][kc], z, 0, 0, 0);
                }
                sc[t] = z;
            }

            // ---- block max per q-row ----
            float mx = sc[0][0];
            #pragma unroll
            for (int t = 0; t < 4; ++t)
                #pragma unroll
                for (int jj = 0; jj < 4; ++jj)
                    mx = fmaxf(mx, sc[t][jj]);
            mx = fmaxf(mx, __shfl_xor(mx, 16, 64));
            mx = fmaxf(mx, __shfl_xor(mx, 32, 64));

            if (it == 0) {
                m[p] = mx;
            } else if (!__all(mx <= m[p] + 8.f)) {
                float mn = fmaxf(m[p], mx);
                float fac = exp2f(m[p] - mn);
                l[p] *= fac; m[p] = mn;
                #pragma unroll
                for (int jj = 0; jj < 4; ++jj) {
                    float fq = __shfl(fac, g * 4 + jj, 64);
                    #pragma unroll
                    for (int t = 0; t < 4; ++t) acc[p][t][jj] *= fq;
                }
            }

            // ---- P = exp2(S - m): packed cvt writes + lane-local row sum ----
            float rs = 0.f;
            #pragma unroll
            for (int t = 0; t < 4; ++t) {
                #pragma unroll
                for (int jjp = 0; jjp < 4; jjp += 2) {
                    float e0 = exp2f(sc[t][jjp]     - m[p]);
                    float e1 = exp2f(sc[t][jjp + 1] - m[p]);
                    rs += e0 + e1;
                    unsigned u;
                    asm("v_cvt_pk_bf16_f32 %0, %1, %2" : "=v"(u) : "v"(e0), "v"(e1));
                    *(unsigned*)(Pw + rl * 128 + (((t * 16 + g * 4 + jjp) * 2) ^ swz)) = u;
                }
            }
            rs += __shfl_xor(rs, 16, 64);
            rs += __shfl_xor(rs, 32, 64);
            l[p] += rs;

            // ---- O += P @ V (wave-private P; staged V) ----
            #pragma unroll
            for (int kc = 0; kc < 2; ++kc) {
                bf16x8 pa = *(const bf16x8*)(Pw + rl * 128 + ((kc * 64 + g * 16) ^ swz));
                #pragma unroll
                for (int t = 0; t < 4; ++t) {
                    bf16x8 vf = *(const bf16x8*)(Vl + t * 2048 + rl * 128 + (((kc * 4 + g) ^ kx) << 4));
                    acc[p][t] = __builtin_amdgcn_mfma_f32_16x16x32_bf16(pa, vf, acc[p][t], 0, 0, 0);
                }
            }
        }
        __syncthreads();   // drains this iter's prefetch; next buffer ready
    }

    // ---- epilogue: redistribute l to acc layout (q = g*4+jj), combine, store ----
    const float lam = lam_p[0];
    float inv0[4], inv1[4];
    #pragma unroll
    for (int jj = 0; jj < 4; ++jj) {
        inv0[jj] = 1.0f / __shfl(l[0], g * 4 + jj, 64);
        inv1[jj] = lam  / __shfl(l[1], g * 4 + jj, 64);
    }
    #pragma unroll
    for (int t = 0; t < 4; ++t)
        #pragma unroll
        for (int jj = 0; jj < 4; ++jj) {
            float o = acc[0][t][jj] * inv0[jj] - acc[1][t][jj] * inv1[jj];
            int s = qbase + g * 4 + jj;
            Ocat[(size_t)s * 1024 + h * 64 + t * 16 + rl] = (short)f2bf(o);
        }
}

// ---------------- output projection GEMM (64x128 tiles, LDS-staged) ----------------
__global__ __launch_bounds__(256) void k_gemm_out(
        const short* __restrict__ Ocat, const short* __restrict__ WoT,
        const float* __restrict__ bo, float* __restrict__ Yws) {
    __shared__ __align__(16) char sA[8192], sB[16384];
    int id = blockIdx.x;
    id = (id & 7) * 32 + (id >> 3);
    const int mbase = (id % 32) * 64;
    const int nbase = (id / 32) * 128;

    f32x4 acc[8];
    #pragma unroll
    for (int i = 0; i < 8; ++i) acc[i] = (f32x4){0.f, 0.f, 0.f, 0.f};

    gemm_core<64, 128, 1, 4>((const char*)Ocat + (size_t)mbase * 2048, 2048,
                             (const char*)WoT + (size_t)nbase * 2048, 2048,
                             1024, sA, sB, acc);

    const int lane = threadIdx.x & 63, wave = threadIdx.x >> 6;
    const int rl = lane & 15, g = lane >> 4;
    #pragma unroll
    for (int f = 0; f < 4; ++f)
        #pragma unroll
        for (int j = 0; j < 2; ++j)
            #pragma unroll
            for (int jj = 0; jj < 4; ++jj) {
                int s = mbase + f * 16 + g * 4 + jj;
                int e = nbase + wave * 32 + j * 16 + rl;
                Yws[(size_t)s * 1024 + e] = acc[f * 2 + j][jj] + bo[e];
            }
}

// ---------------- LayerNorm + final scale ----------------
__global__ __launch_bounds__(256) void k_ln(
        const float* __restrict__ Yws, const float* __restrict__ gamma,
        const float* __restrict__ beta, float* __restrict__ out) {
    const int s = blockIdx.x;
    const int tid = threadIdx.x;
    f32x4 y = ((const f32x4*)(Yws + (size_t)s * 1024))[tid];
    float sum = y[0] + y[1] + y[2] + y[3];
    float sq  = y[0]*y[0] + y[1]*y[1] + y[2]*y[2] + y[3]*y[3];
    #pragma unroll
    for (int off = 1; off < 64; off <<= 1) {
        sum += __shfl_xor(sum, off, 64);
        sq  += __shfl_xor(sq,  off, 64);
    }
    __shared__ float ls[2][4];
    const int wave = tid >> 6, lane = tid & 63;
    if (lane == 0) { ls[0][wave] = sum; ls[1][wave] = sq; }
    __syncthreads();
    sum = ls[0][0] + ls[0][1] + ls[0][2] + ls[0][3];
    sq  = ls[1][0] + ls[1][1] + ls[1][2] + ls[1][3];
    const float mu = sum * (1.f / 1024.f);
    const float var = sq * (1.f / 1024.f) - mu * mu;
    const float rstd = rsqrtf(var + 1e-5f);
    f32x4 gg = ((const f32x4*)gamma)[tid];
    f32x4 bb = ((const f32x4*)beta)[tid];
    f32x4 o;
    #pragma unroll
    for (int k = 0; k < 4; ++k)
        o[k] = ((y[k] - mu) * rstd * gg[k] + bb[k]) * 0.2f;
    ((f32x4*)(out + (size_t)s * 1024))[tid] = o;
}

extern "C" void kernel_launch(void* const* d_in, const int* in_sizes, int n_in,
                              void* d_out, int out_size, void* d_ws, size_t ws_size,
                              hipStream_t stream) {
    const float* X     = (const float*)d_in[0];
    const float* Wq    = (const float*)d_in[1];
    const float* bq    = (const float*)d_in[2];
    const float* Wk    = (const float*)d_in[3];
    const float* bk    = (const float*)d_in[4];
    const float* Wv    = (const float*)d_in[5];
    const float* bv    = (const float*)d_in[6];
    const float* Wo    = (const float*)d_in[7];
    const float* bo    = (const float*)d_in[8];
    const float* gamma = (const float*)d_in[9];
    const float* beta  = (const float*)d_in[10];
    const float* lam   = (const float*)d_in[11];
    float* out = (float*)d_out;

    char* ws = (char*)d_ws;
    const size_t MB = 1u << 20;
    short* Xb  = (short*)(ws + 0);        // 4MB (dead after qkv gemm)
    short* WqT = (short*)(ws + 4 * MB);   // 4MB (dead after qkv gemm)
    short* WkT = (short*)(ws + 8 * MB);   // 4MB
    short* WvT = (short*)(ws + 12 * MB);  // 2MB
    short* WoT = (short*)(ws + 14 * MB);  // 2MB
    short* Qh  = (short*)(ws + 16 * MB);  // 8MB
    short* Kh  = (short*)(ws + 24 * MB);  // 8MB
    short* Vt  = (short*)(ws + 32 * MB);  // 4MB
    short* Oc  = (short*)(ws + 36 * MB);  // 4MB
    float* Yws = (float*)(ws + 0);        // 8MB, aliases Xb+WqT (both dead by then)

    k_convert_x<<<dim3(2048), dim3(256), 0, stream>>>(X, Xb, (S_LEN * EDIM) / 4);
    k_transpose_cvt<<<dim3(4, 32, 16), dim3(32, 8), 0, stream>>>(Wq, WqT, 1024, 128);
    k_transpose_cvt<<<dim3(4, 32, 16), dim3(32, 8), 0, stream>>>(Wk, WkT, 1024, 128);
    k_transpose_cvt<<<dim3(2, 32, 16), dim3(32, 8), 0, stream>>>(Wv, WvT, 1024, 64);
    k_transpose_cvt<<<dim3(32, 32, 1), dim3(32, 8), 0, stream>>>(Wo, WoT, 1024, 1024);
    k_gemm_qkv<<<dim3(640), dim3(256), 0, stream>>>(Xb, WqT, WkT, WvT, bq, bk, bv, Qh, Kh, Vt);
    k_attn<<<dim3(16, 16), dim3(512), 0, stream>>>(Qh, Kh, Vt, lam, Oc);
    k_gemm_out<<<dim3(256), dim3(256), 0, stream>>>(Oc, WoT, bo, Yws);
    k_ln<<<dim3(2048), dim3(256), 0, stream>>>(Yws, gamma, beta, out);
}

// Round 10
// 179.395 us; speedup vs baseline: 1.0094x; 1.0094x over previous
//
#include <hip/hip_runtime.h>

#define S_LEN 2048
#define EDIM  1024
#define HEADS 16
#define DHEAD 64

typedef __attribute__((ext_vector_type(8))) short bf16x8;
typedef __attribute__((ext_vector_type(4))) short short4v;
typedef __attribute__((ext_vector_type(4))) float f32x4;

__device__ inline unsigned short f2bf(float f) {
    unsigned int u = __float_as_uint(f);
    unsigned int r = (u + 0x7FFFu + ((u >> 16) & 1u)) >> 16;
    return (unsigned short)r;
}
__device__ inline float bf2f(unsigned short b) {
    return __uint_as_float(((unsigned int)b) << 16);
}
__device__ inline void load_lds16(const void* g, void* l) {
    __builtin_amdgcn_global_load_lds(
        (const __attribute__((address_space(1))) unsigned int*)g,
        (__attribute__((address_space(3))) unsigned int*)l, 16, 0, 0);
}

// ---------------- X fp32 -> bf16 ----------------
__global__ void k_convert_x(const float* __restrict__ x, short* __restrict__ xb, int n4) {
    int i = blockIdx.x * blockDim.x + threadIdx.x;
    if (i >= n4) return;
    f32x4 v = ((const f32x4*)x)[i];
    short4v o;
    o[0] = (short)f2bf(v[0]); o[1] = (short)f2bf(v[1]);
    o[2] = (short)f2bf(v[2]); o[3] = (short)f2bf(v[3]);
    ((short4v*)xb)[i] = o;
}

// ---------------- tiled transpose + fp32->bf16: in[R][C] -> out[C][R], batched over z ----------------
__global__ void k_transpose_cvt(const float* __restrict__ in, short* __restrict__ out, int R, int C) {
    __shared__ float tile[32][33];
    const int b = blockIdx.z;
    in  += (size_t)b * R * C;
    out += (size_t)b * R * C;
    const int c0 = blockIdx.x * 32, r0 = blockIdx.y * 32;
    #pragma unroll
    for (int yy = 0; yy < 4; ++yy) {
        int r = r0 + threadIdx.y + yy * 8, c = c0 + threadIdx.x;
        tile[threadIdx.y + yy * 8][threadIdx.x] = (r < R && c < C) ? in[(size_t)r * C + c] : 0.f;
    }
    __syncthreads();
    #pragma unroll
    for (int yy = 0; yy < 4; ++yy) {
        int c = c0 + threadIdx.y + yy * 8, r = r0 + threadIdx.x;
        if (c < C && r < R) out[(size_t)c * R + r] = (short)f2bf(tile[threadIdx.x][threadIdx.y + yy * 8]);
    }
}

// ---------------- LDS-staged MFMA GEMM core (m97 structure) ----------------
template<int BM, int BN, int WR, int WC>
__device__ inline void gemm_core(const char* Ag, int ldaB, const char* Bg, int ldbB,
                                 int K, char* sA, char* sB, f32x4* acc) {
    constexpr int FM = BM / (WR * 16), FN = BN / (WC * 16);
    constexpr int RA = BM / 32, RB = BN / 32;
    const int lane = threadIdx.x & 63, wave = threadIdx.x >> 6;
    const int rl = lane & 15, g = lane >> 4;
    const int wrow = (wave / WC) * (BM / WR);
    const int wcol = (wave % WC) * (BN / WC);
    const int lr = lane >> 3;                 // row within 8-row staging group
    const int lc = ((lane & 7) ^ lr) << 4;    // inverse-swizzled 16B chunk
    const char* aSrc = Ag + (size_t)(wave * 8 + lr) * ldaB + lc;
    const char* bSrc = Bg + (size_t)(wave * 8 + lr) * ldbB + lc;

    for (int t = 0; t < K / 64; ++t) {
        __syncthreads();
        #pragma unroll
        for (int i = 0; i < RA; ++i)
            load_lds16(aSrc + (size_t)t * 128 + (size_t)i * 32 * ldaB, sA + (i * 4 + wave) * 1024);
        #pragma unroll
        for (int i = 0; i < RB; ++i)
            load_lds16(bSrc + (size_t)t * 128 + (size_t)i * 32 * ldbB, sB + (i * 4 + wave) * 1024);
        __syncthreads();
        #pragma unroll
        for (int kk = 0; kk < 2; ++kk) {
            bf16x8 af[FM], bf[FN];
            #pragma unroll
            for (int f = 0; f < FM; ++f) {
                const int r = wrow + f * 16 + rl;
                af[f] = *(const bf16x8*)(sA + r * 128 + (((kk * 4 + g) ^ (r & 7)) << 4));
            }
            #pragma unroll
            for (int j = 0; j < FN; ++j) {
                const int r = wcol + j * 16 + rl;
                bf[j] = *(const bf16x8*)(sB + r * 128 + (((kk * 4 + g) ^ (r & 7)) << 4));
            }
            #pragma unroll
            for (int f = 0; f < FM; ++f)
                #pragma unroll
                for (int j = 0; j < FN; ++j)
                    acc[f * FN + j] = __builtin_amdgcn_mfma_f32_16x16x32_bf16(af[f], bf[j], acc[f * FN + j], 0, 0, 0);
        }
    }
}

// ---------------- QKV projection GEMM (128x128 tiles, LDS-staged) ----------------
__global__ __launch_bounds__(256) void k_gemm_qkv(
        const short* __restrict__ Xb,
        const short* __restrict__ WqT, const short* __restrict__ WkT, const short* __restrict__ WvT,
        const float* __restrict__ bq, const float* __restrict__ bk, const float* __restrict__ bv,
        short* __restrict__ Qh, short* __restrict__ Kh, short* __restrict__ Vt) {
    __shared__ __align__(16) char sA[16384], sB[16384];
    int id = blockIdx.x;
    id = (id & 7) * 80 + (id >> 3);           // XCD-contiguous chunks
    const int mbase = (id % 16) * 128;
    const int y = id / 16;

    const short* Bt; const float* bias; int nbase; int which;
    if (y < 16)      { which = 0; Bt = WqT; bias = bq; nbase = y * 128; }
    else if (y < 32) { which = 1; Bt = WkT; bias = bk; nbase = (y - 16) * 128; }
    else             { which = 2; Bt = WvT; bias = bv; nbase = (y - 32) * 128; }

    f32x4 acc[16];
    #pragma unroll
    for (int i = 0; i < 16; ++i) acc[i] = (f32x4){0.f, 0.f, 0.f, 0.f};

    gemm_core<128, 128, 2, 2>((const char*)Xb + (size_t)mbase * 2048, 2048,
                              (const char*)Bt + (size_t)nbase * 2048, 2048,
                              EDIM, sA, sB, acc);

    const int lane = threadIdx.x & 63, wave = threadIdx.x >> 6;
    const int wr = (wave >> 1) * 64, wc = (wave & 1) * 64;
    const int rl = lane & 15, g = lane >> 4;
    const float qscale = 0.125f * 1.44269504088896f;
    #pragma unroll
    for (int i = 0; i < 4; ++i)
        #pragma unroll
        for (int j = 0; j < 4; ++j)
            #pragma unroll
            for (int jj = 0; jj < 4; ++jj) {
                int s = mbase + wr + i * 16 + g * 4 + jj;
                int n = nbase + wc + j * 16 + rl;
                float v = acc[i * 4 + j][jj] + bias[n];
                if (which == 0) v *= qscale;
                short b16 = (short)f2bf(v);
                if (which == 0)      Qh[((size_t)(n >> 7) * S_LEN + s) * 128 + (n & 127)] = b16;
                else if (which == 1) Kh[((size_t)(n >> 7) * S_LEN + s) * 128 + (n & 127)] = b16;
                else                 Vt[(size_t)n * S_LEN + s] = b16;
            }
}

// ---------------- differential flash attention, v8: v5 math + KVBLK=32 + dbuf prefetch ----------------
// grid (S/64, H), 512 threads. Waves 0-3: q-rows (w&3)*16.., kv [0,1024);
// waves 4-7: same q-rows, kv [1024,2048). KVBLK=32; K(8KB)+V(4KB) per group
// DOUBLE-BUFFERED with issue-early STAGE (one barrier/iter: the vmcnt drain
// lands after a full compute phase). P = 2KB/wave. LDS = 32K(K)+16K(V)+16K(P)
// = 64KB -> 2 blocks/CU = 16 waves/CU = 4 waves/SIMD WITH prefetch.
// Numeric path identical to the verified v5 (absmax 5.86e-3).
__global__ __launch_bounds__(512, 4) void k_attn(
        const short* __restrict__ Qh, const short* __restrict__ Kh,
        const short* __restrict__ Vt, const float* __restrict__ lam_p,
        short* __restrict__ Ocat) {
    __shared__ __align__(16) char smem[65536];

    const int lane = threadIdx.x & 63, wave = threadIdx.x >> 6;
    const int rl = lane & 15, g = lane >> 4;
    const int qw = wave & 3, kvg = wave >> 2;
    const int h = blockIdx.y;
    const int qbase = blockIdx.x * 64 + qw * 16;
    const int kx = rl & 7;           // K-row swizzle key (256B rows, 16 chunks)
    const int px = (rl & 3) << 4;    // P/V-row swizzle key (64B rows, 4 chunks)

    char* Kg0 = smem + kvg * 16384;            // 2 bufs x 8KB: [32 kv][256B]
    char* Vg0 = smem + 32768 + kvg * 8192;     // 2 bufs x 4KB: [64 d][64B]
    char* Pw  = smem + 49152 + wave * 2048;    // [2p][16 q][64B]

    const char* Kgb = (const char*)(Kh + (size_t)h * S_LEN * 128);
    const char* Vgb = (const char*)(Vt + (size_t)h * DHEAD * S_LEN);
    const short* Qp = Qh + (size_t)h * S_LEN * 128;

    // staging: per iter per group = 8 K-chunks + 4 V-chunks; wave qw does
    // K chunks {2qw, 2qw+1} and V chunk {qw}. Inverse swizzle on global source.
    const int kc0 = qw * 2, kc1 = qw * 2 + 1;
    const int kofs0 = (lane >> 4) * 256 + (((lane & 15) ^ (lane >> 4)) << 4);        // even chunk: row&7 = lane>>4
    const int kofs1 = (lane >> 4) * 256 + (((lane & 15) ^ ((lane >> 4) + 4)) << 4);  // odd chunk:  row&7 = 4+lane>>4
    const int vofs  = (lane >> 2) * 4096 + (((lane & 3) ^ ((lane >> 2) & 3)) << 4);  // row&3 = (lane>>2)&3

    auto STAGE = [&](int b, int it) {
        const size_t kv0 = (size_t)(kvg * 1024 + it * 32);
        char* kb = Kg0 + b * 8192;
        char* vb = Vg0 + b * 4096;
        load_lds16(Kgb + (kv0 + (size_t)kc0 * 4) * 256 + kofs0, kb + kc0 * 1024);
        load_lds16(Kgb + (kv0 + (size_t)kc1 * 4) * 256 + kofs1, kb + kc1 * 1024);
        load_lds16(Vgb + (size_t)(qw * 16) * 4096 + kv0 * 2 + vofs, vb + qw * 1024);
    };

    STAGE(0, 0);

    bf16x8 qf[2][2];
    #pragma unroll
    for (int p = 0; p < 2; ++p)
        #pragma unroll
        for (int kc = 0; kc < 2; ++kc)
            qf[p][kc] = *(const bf16x8*)&Qp[(size_t)(qbase + rl) * 128 + p * 64 + kc * 32 + g * 8];

    f32x4 acc[2][4];
    float m[2], l[2];
    #pragma unroll
    for (int p = 0; p < 2; ++p) {
        #pragma unroll
        for (int t = 0; t < 4; ++t) acc[p][t] = (f32x4){0.f, 0.f, 0.f, 0.f};
        m[p] = 0.f; l[p] = 0.f;
    }

    __syncthreads();   // prologue stage drained

    const int NIT = 1024 / 32;
    for (int it = 0; it < NIT; ++it) {
        const int cur = it & 1;
        if (it + 1 < NIT) STAGE(cur ^ 1, it + 1);   // issue-early prefetch
        const char* kb = Kg0 + cur * 8192;
        const char* vb = Vg0 + cur * 4096;

        #pragma unroll
        for (int p = 0; p < 2; ++p) {
            // ---- QK^T (swapped: mfma(K,Q)); Q pre-scaled -> exp2 domain ----
            f32x4 sc[2];
            #pragma unroll
            for (int t = 0; t < 2; ++t) {
                f32x4 z = (f32x4){0.f, 0.f, 0.f, 0.f};
                #pragma unroll
                for (int kc = 0; kc < 2; ++kc) {
                    bf16x8 kf = *(const bf16x8*)(kb + t * 4096 + rl * 256 + (((p * 8 + kc * 4 + g) ^ kx) << 4));
                    z = __builtin_amdgcn_mfma_f32_16x16x32_bf16(kf, qf[p][kc], z, 0, 0, 0);
                }
                sc[t] = z;
            }

            // ---- block max per q-row (lane-local + 2 shuffles) ----
            float mx = sc[0][0];
            #pragma unroll
            for (int t = 0; t < 2; ++t)
                #pragma unroll
                for (int jj = 0; jj < 4; ++jj)
                    mx = fmaxf(mx, sc[t][jj]);
            mx = fmaxf(mx, __shfl_xor(mx, 16, 64));
            mx = fmaxf(mx, __shfl_xor(mx, 32, 64));

            if (it == 0) {
                m[p] = mx;
            } else if (!__all(mx <= m[p] + 8.f)) {
                float mn = fmaxf(m[p], mx);
                float fac = exp2f(m[p] - mn);
                l[p] *= fac; m[p] = mn;
                #pragma unroll
                for (int jj = 0; jj < 4; ++jj) {
                    float fq = __shfl(fac, g * 4 + jj, 64);
                    #pragma unroll
                    for (int t = 0; t < 4; ++t) acc[p][t][jj] *= fq;
                }
            }

            // ---- P = exp2(S - m): packed cvt writes + lane-local row sum ----
            float rs = 0.f;
            #pragma unroll
            for (int t = 0; t < 2; ++t) {
                #pragma unroll
                for (int jjp = 0; jjp < 4; jjp += 2) {
                    float e0 = exp2f(sc[t][jjp]     - m[p]);
                    float e1 = exp2f(sc[t][jjp + 1] - m[p]);
                    rs += e0 + e1;
                    unsigned u;
                    asm("v_cvt_pk_bf16_f32 %0, %1, %2" : "=v"(u) : "v"(e0), "v"(e1));
                    *(unsigned*)(Pw + p * 1024 + rl * 64 + (((t * 16 + g * 4 + jjp) * 2) ^ px)) = u;
                }
            }
            rs += __shfl_xor(rs, 16, 64);
            rs += __shfl_xor(rs, 32, 64);
            l[p] += rs;

            // ---- O += P @ V (wave-private P as A; staged V as B; K=32) ----
            bf16x8 pa = *(const bf16x8*)(Pw + p * 1024 + rl * 64 + ((g * 16) ^ px));
            #pragma unroll
            for (int t = 0; t < 4; ++t) {
                bf16x8 vf = *(const bf16x8*)(vb + (t * 16 + rl) * 64 + (((g) ^ (rl & 3)) << 4));
                acc[p][t] = __builtin_amdgcn_mfma_f32_16x16x32_bf16(pa, vf, acc[p][t], 0, 0, 0);
            }
        }
        __syncthreads();   // drains this iter's prefetch; next buffer ready
    }

    // ---- exchange partials through LDS (staging regions dead after final barrier) ----
    {
        unsigned short* Xw = (unsigned short*)(smem + wave * 4096);  // [2][16][64] bf16
        float* ML = (float*)(smem + 32768);                          // [8w][2p][{m,l}][16]
        #pragma unroll
        for (int p = 0; p < 2; ++p) {
            #pragma unroll
            for (int t = 0; t < 4; ++t)
                #pragma unroll
                for (int jj = 0; jj < 4; ++jj)
                    Xw[p * 1024 + (g * 4 + jj) * 64 + t * 16 + rl] = f2bf(acc[p][t][jj]);
            if (g == 0) {
                ML[(wave * 2 + p) * 32 + rl]      = m[p];
                ML[(wave * 2 + p) * 32 + 16 + rl] = l[p];
            }
        }
    }
    __syncthreads();

    // ---- combine the 2 kv-group partials; thread -> (q = tid>>3, d0 = (tid&7)*8) ----
    {
        const int q = threadIdx.x >> 3, d0 = (threadIdx.x & 7) * 8;
        const int q15 = q & 15, wa = q >> 4, wb = (q >> 4) + 4;
        const float* ML = (const float*)(smem + 32768);
        const float lam = lam_p[0];
        float res[2][8];
        float invL[2];
        #pragma unroll
        for (int p = 0; p < 2; ++p) {
            float ma = ML[(wa * 2 + p) * 32 + q15], la = ML[(wa * 2 + p) * 32 + 16 + q15];
            float mb = ML[(wb * 2 + p) * 32 + q15], lb = ML[(wb * 2 + p) * 32 + 16 + q15];
            float ms = fmaxf(ma, mb);
            float fa = exp2f(ma - ms), fb = exp2f(mb - ms);
            invL[p] = 1.0f / (fa * la + fb * lb);
            const unsigned short* xa = (const unsigned short*)(smem + wa * 4096 + p * 2048 + q15 * 128 + d0 * 2);
            const unsigned short* xb = (const unsigned short*)(smem + wb * 4096 + p * 2048 + q15 * 128 + d0 * 2);
            #pragma unroll
            for (int k = 0; k < 8; ++k)
                res[p][k] = fa * bf2f(xa[k]) + fb * bf2f(xb[k]);
        }
        bf16x8 ov;
        #pragma unroll
        for (int k = 0; k < 8; ++k)
            ov[k] = (short)f2bf(res[0][k] * invL[0] - lam * res[1][k] * invL[1]);
        *(bf16x8*)&Ocat[(size_t)(blockIdx.x * 64 + q) * 1024 + h * 64 + d0] = ov;
    }
}

// ---------------- output projection GEMM (64x128 tiles, LDS-staged) ----------------
__global__ __launch_bounds__(256) void k_gemm_out(
        const short* __restrict__ Ocat, const short* __restrict__ WoT,
        const float* __restrict__ bo, float* __restrict__ Yws) {
    __shared__ __align__(16) char sA[8192], sB[16384];
    int id = blockIdx.x;
    id = (id & 7) * 32 + (id >> 3);
    const int mbase = (id % 32) * 64;
    const int nbase = (id / 32) * 128;

    f32x4 acc[8];
    #pragma unroll
    for (int i = 0; i < 8; ++i) acc[i] = (f32x4){0.f, 0.f, 0.f, 0.f};

    gemm_core<64, 128, 1, 4>((const char*)Ocat + (size_t)mbase * 2048, 2048,
                             (const char*)WoT + (size_t)nbase * 2048, 2048,
                             1024, sA, sB, acc);

    const int lane = threadIdx.x & 63, wave = threadIdx.x >> 6;
    const int rl = lane & 15, g = lane >> 4;
    #pragma unroll
    for (int f = 0; f < 4; ++f)
        #pragma unroll
        for (int j = 0; j < 2; ++j)
            #pragma unroll
            for (int jj = 0; jj < 4; ++jj) {
                int s = mbase + f * 16 + g * 4 + jj;
                int e = nbase + wave * 32 + j * 16 + rl;
                Yws[(size_t)s * 1024 + e] = acc[f * 2 + j][jj] + bo[e];
            }
}

// ---------------- LayerNorm + final scale ----------------
__global__ __launch_bounds__(256) void k_ln(
        const float* __restrict__ Yws, const float* __restrict__ gamma,
        const float* __restrict__ beta, float* __restrict__ out) {
    const int s = blockIdx.x;
    const int tid = threadIdx.x;
    f32x4 y = ((const f32x4*)(Yws + (size_t)s * 1024))[tid];
    float sum = y[0] + y[1] + y[2] + y[3];
    float sq  = y[0]*y[0] + y[1]*y[1] + y[2]*y[2] + y[3]*y[3];
    #pragma unroll
    for (int off = 1; off < 64; off <<= 1) {
        sum += __shfl_xor(sum, off, 64);
        sq  += __shfl_xor(sq,  off, 64);
    }
    __shared__ float ls[2][4];
    const int wave = tid >> 6, lane = tid & 63;
    if (lane == 0) { ls[0][wave] = sum; ls[1][wave] = sq; }
    __syncthreads();
    sum = ls[0][0] + ls[0][1] + ls[0][2] + ls[0][3];
    sq  = ls[1][0] + ls[1][1] + ls[1][2] + ls[1][3];
    const float mu = sum * (1.f / 1024.f);
    const float var = sq * (1.f / 1024.f) - mu * mu;
    const float rstd = rsqrtf(var + 1e-5f);
    f32x4 gg = ((const f32x4*)gamma)[tid];
    f32x4 bb = ((const f32x4*)beta)[tid];
    f32x4 o;
    #pragma unroll
    for (int k = 0; k < 4; ++k)
        o[k] = ((y[k] - mu) * rstd * gg[k] + bb[k]) * 0.2f;
    ((f32x4*)(out + (size_t)s * 1024))[tid] = o;
}

extern "C" void kernel_launch(void* const* d_in, const int* in_sizes, int n_in,
                              void* d_out, int out_size, void* d_ws, size_t ws_size,
                              hipStream_t stream) {
    const float* X     = (const float*)d_in[0];
    const float* Wq    = (const float*)d_in[1];
    const float* bq    = (const float*)d_in[2];
    const float* Wk    = (const float*)d_in[3];
    const float* bk    = (const float*)d_in[4];
    const float* Wv    = (const float*)d_in[5];
    const float* bv    = (const float*)d_in[6];
    const float* Wo    = (const float*)d_in[7];
    const float* bo    = (const float*)d_in[8];
    const float* gamma = (const float*)d_in[9];
    const float* beta  = (const float*)d_in[10];
    const float* lam   = (const float*)d_in[11];
    float* out = (float*)d_out;

    char* ws = (char*)d_ws;
    const size_t MB = 1u << 20;
    short* Xb  = (short*)(ws + 0);        // 4MB (dead after qkv gemm)
    short* WqT = (short*)(ws + 4 * MB);   // 4MB (dead after qkv gemm)
    short* WkT = (short*)(ws + 8 * MB);   // 4MB
    short* WvT = (short*)(ws + 12 * MB);  // 2MB
    short* WoT = (short*)(ws + 14 * MB);  // 2MB
    short* Qh  = (short*)(ws + 16 * MB);  // 8MB
    short* Kh  = (short*)(ws + 24 * MB);  // 8MB
    short* Vt  = (short*)(ws + 32 * MB);  // 4MB
    short* Oc  = (short*)(ws + 36 * MB);  // 4MB
    float* Yws = (float*)(ws + 0);        // 8MB, aliases Xb+WqT (both dead by then)

    k_convert_x<<<dim3(2048), dim3(256), 0, stream>>>(X, Xb, (S_LEN * EDIM) / 4);
    k_transpose_cvt<<<dim3(4, 32, 16), dim3(32, 8), 0, stream>>>(Wq, WqT, 1024, 128);
    k_transpose_cvt<<<dim3(4, 32, 16), dim3(32, 8), 0, stream>>>(Wk, WkT, 1024, 128);
    k_transpose_cvt<<<dim3(2, 32, 16), dim3(32, 8), 0, stream>>>(Wv, WvT, 1024, 64);
    k_transpose_cvt<<<dim3(32, 32, 1), dim3(32, 8), 0, stream>>>(Wo, WoT, 1024, 1024);
    k_gemm_qkv<<<dim3(640), dim3(256), 0, stream>>>(Xb, WqT, WkT, WvT, bq, bk, bv, Qh, Kh, Vt);
    k_attn<<<dim3(32, 16), dim3(512), 0, stream>>>(Qh, Kh, Vt, lam, Oc);
    k_gemm_out<<<dim3(256), dim3(256), 0, stream>>>(Oc, WoT, bo, Yws);
    k_ln<<<dim3(2048), dim3(256), 0, stream>>>(Yws, gamma, beta, out);
}

// Round 11
// 175.967 us; speedup vs baseline: 1.0291x; 1.0195x over previous
//
#include <hip/hip_runtime.h>

#define S_LEN 2048
#define EDIM  1024
#define HEADS 16
#define DHEAD 64

typedef __attribute__((ext_vector_type(8))) short bf16x8;
typedef __attribute__((ext_vector_type(4))) short short4v;
typedef __attribute__((ext_vector_type(4))) float f32x4;

__device__ inline unsigned short f2bf(float f) {
    unsigned int u = __float_as_uint(f);
    unsigned int r = (u + 0x7FFFu + ((u >> 16) & 1u)) >> 16;
    return (unsigned short)r;
}
__device__ inline float bf2f(unsigned short b) {
    return __uint_as_float(((unsigned int)b) << 16);
}
__device__ inline void load_lds16(const void* g, void* l) {
    __builtin_amdgcn_global_load_lds(
        (const __attribute__((address_space(1))) unsigned int*)g,
        (__attribute__((address_space(3))) unsigned int*)l, 16, 0, 0);
}

// ---------------- X fp32 -> bf16 ----------------
__global__ void k_convert_x(const float* __restrict__ x, short* __restrict__ xb, int n4) {
    int i = blockIdx.x * blockDim.x + threadIdx.x;
    if (i >= n4) return;
    f32x4 v = ((const f32x4*)x)[i];
    short4v o;
    o[0] = (short)f2bf(v[0]); o[1] = (short)f2bf(v[1]);
    o[2] = (short)f2bf(v[2]); o[3] = (short)f2bf(v[3]);
    ((short4v*)xb)[i] = o;
}

// ---------------- tiled transpose + fp32->bf16: in[R][C] -> out[C][R], batched over z ----------------
__global__ void k_transpose_cvt(const float* __restrict__ in, short* __restrict__ out, int R, int C) {
    __shared__ float tile[32][33];
    const int b = blockIdx.z;
    in  += (size_t)b * R * C;
    out += (size_t)b * R * C;
    const int c0 = blockIdx.x * 32, r0 = blockIdx.y * 32;
    #pragma unroll
    for (int yy = 0; yy < 4; ++yy) {
        int r = r0 + threadIdx.y + yy * 8, c = c0 + threadIdx.x;
        tile[threadIdx.y + yy * 8][threadIdx.x] = (r < R && c < C) ? in[(size_t)r * C + c] : 0.f;
    }
    __syncthreads();
    #pragma unroll
    for (int yy = 0; yy < 4; ++yy) {
        int c = c0 + threadIdx.y + yy * 8, r = r0 + threadIdx.x;
        if (c < C && r < R) out[(size_t)c * R + r] = (short)f2bf(tile[threadIdx.x][threadIdx.y + yy * 8]);
    }
}

// ---------------- LDS-staged MFMA GEMM core (m97 structure) ----------------
template<int BM, int BN, int WR, int WC>
__device__ inline void gemm_core(const char* Ag, int ldaB, const char* Bg, int ldbB,
                                 int K, char* sA, char* sB, f32x4* acc) {
    constexpr int FM = BM / (WR * 16), FN = BN / (WC * 16);
    constexpr int RA = BM / 32, RB = BN / 32;
    const int lane = threadIdx.x & 63, wave = threadIdx.x >> 6;
    const int rl = lane & 15, g = lane >> 4;
    const int wrow = (wave / WC) * (BM / WR);
    const int wcol = (wave % WC) * (BN / WC);
    const int lr = lane >> 3;                 // row within 8-row staging group
    const int lc = ((lane & 7) ^ lr) << 4;    // inverse-swizzled 16B chunk
    const char* aSrc = Ag + (size_t)(wave * 8 + lr) * ldaB + lc;
    const char* bSrc = Bg + (size_t)(wave * 8 + lr) * ldbB + lc;

    for (int t = 0; t < K / 64; ++t) {
        __syncthreads();
        #pragma unroll
        for (int i = 0; i < RA; ++i)
            load_lds16(aSrc + (size_t)t * 128 + (size_t)i * 32 * ldaB, sA + (i * 4 + wave) * 1024);
        #pragma unroll
        for (int i = 0; i < RB; ++i)
            load_lds16(bSrc + (size_t)t * 128 + (size_t)i * 32 * ldbB, sB + (i * 4 + wave) * 1024);
        __syncthreads();
        #pragma unroll
        for (int kk = 0; kk < 2; ++kk) {
            bf16x8 af[FM], bf[FN];
            #pragma unroll
            for (int f = 0; f < FM; ++f) {
                const int r = wrow + f * 16 + rl;
                af[f] = *(const bf16x8*)(sA + r * 128 + (((kk * 4 + g) ^ (r & 7)) << 4));
            }
            #pragma unroll
            for (int j = 0; j < FN; ++j) {
                const int r = wcol + j * 16 + rl;
                bf[j] = *(const bf16x8*)(sB + r * 128 + (((kk * 4 + g) ^ (r & 7)) << 4));
            }
            #pragma unroll
            for (int f = 0; f < FM; ++f)
                #pragma unroll
                for (int j = 0; j < FN; ++j)
                    acc[f * FN + j] = __builtin_amdgcn_mfma_f32_16x16x32_bf16(af[f], bf[j], acc[f * FN + j], 0, 0, 0);
        }
    }
}

// ---------------- QKV projection GEMM (128x128 tiles, LDS-staged) ----------------
__global__ __launch_bounds__(256) void k_gemm_qkv(
        const short* __restrict__ Xb,
        const short* __restrict__ WqT, const short* __restrict__ WkT, const short* __restrict__ WvT,
        const float* __restrict__ bq, const float* __restrict__ bk, const float* __restrict__ bv,
        short* __restrict__ Qh, short* __restrict__ Kh, short* __restrict__ Vt) {
    __shared__ __align__(16) char sA[16384], sB[16384];
    int id = blockIdx.x;
    id = (id & 7) * 80 + (id >> 3);           // XCD-contiguous chunks
    const int mbase = (id % 16) * 128;
    const int y = id / 16;

    const short* Bt; const float* bias; int nbase; int which;
    if (y < 16)      { which = 0; Bt = WqT; bias = bq; nbase = y * 128; }
    else if (y < 32) { which = 1; Bt = WkT; bias = bk; nbase = (y - 16) * 128; }
    else             { which = 2; Bt = WvT; bias = bv; nbase = (y - 32) * 128; }

    f32x4 acc[16];
    #pragma unroll
    for (int i = 0; i < 16; ++i) acc[i] = (f32x4){0.f, 0.f, 0.f, 0.f};

    gemm_core<128, 128, 2, 2>((const char*)Xb + (size_t)mbase * 2048, 2048,
                              (const char*)Bt + (size_t)nbase * 2048, 2048,
                              EDIM, sA, sB, acc);

    const int lane = threadIdx.x & 63, wave = threadIdx.x >> 6;
    const int wr = (wave >> 1) * 64, wc = (wave & 1) * 64;
    const int rl = lane & 15, g = lane >> 4;
    const float qscale = 0.125f * 1.44269504088896f;
    #pragma unroll
    for (int i = 0; i < 4; ++i)
        #pragma unroll
        for (int j = 0; j < 4; ++j)
            #pragma unroll
            for (int jj = 0; jj < 4; ++jj) {
                int s = mbase + wr + i * 16 + g * 4 + jj;
                int n = nbase + wc + j * 16 + rl;
                float v = acc[i * 4 + j][jj] + bias[n];
                if (which == 0) v *= qscale;
                short b16 = (short)f2bf(v);
                if (which == 0)      Qh[((size_t)(n >> 7) * S_LEN + s) * 128 + (n & 127)] = b16;
                else if (which == 1) Kh[((size_t)(n >> 7) * S_LEN + s) * 128 + (n & 127)] = b16;
                else                 Vt[(size_t)n * S_LEN + s] = b16;
            }
}

// ---------------- differential flash attention, v9 ----------------
// v8 structure (8 waves, 2-way in-block kv-split, KVBLK=32, dbuf K prefetch)
// with the two conflict sources fixed:
//  - P back to [16 q][128B] rows (p folded into the row; swz = (rl&7)<<4) -> 2-way max
//  - V read directly from GLOBAL into registers (no V LDS tile at all); the 4
//    loads/iter have no in-iter deps so L2 latency hides under QK+softmax.
// LDS = K dbuf 32KB + P 16KB = 48KB. Numeric path identical to v5/v8.
__global__ __launch_bounds__(512, 4) void k_attn(
        const short* __restrict__ Qh, const short* __restrict__ Kh,
        const short* __restrict__ Vt, const float* __restrict__ lam_p,
        short* __restrict__ Ocat) {
    __shared__ __align__(16) char smem[49152];

    const int lane = threadIdx.x & 63, wave = threadIdx.x >> 6;
    const int rl = lane & 15, g = lane >> 4;
    const int qw = wave & 3, kvg = wave >> 2;
    const int h = blockIdx.y;
    const int qbase = blockIdx.x * 64 + qw * 16;
    const int kx = rl & 7;              // K-row swizzle key (256B rows)
    const int swz = (rl & 7) << 4;      // P-row swizzle key (128B rows)

    char* Kg0 = smem + kvg * 16384;            // 2 bufs x 8KB: [32 kv][256B]
    char* Pw  = smem + 32768 + wave * 2048;    // [16 q][128B] = {p0 64B | p1 64B} swizzled

    const char* Kgb = (const char*)(Kh + (size_t)h * S_LEN * 128);
    const char* Vgb = (const char*)(Vt + (size_t)h * DHEAD * S_LEN);
    const short* Qp = Qh + (size_t)h * S_LEN * 128;

    // K staging: 8 chunks of 1KB per group per iter; wave qw does chunks {2qw, 2qw+1}
    const int kc0 = qw * 2, kc1 = qw * 2 + 1;
    const int kofs0 = (lane >> 4) * 256 + (((lane & 15) ^ (lane >> 4)) << 4);
    const int kofs1 = (lane >> 4) * 256 + (((lane & 15) ^ ((lane >> 4) + 4)) << 4);

    auto STAGE = [&](int b, int it) {
        const size_t kv0 = (size_t)(kvg * 1024 + it * 32);
        char* kb = Kg0 + b * 8192;
        load_lds16(Kgb + (kv0 + (size_t)kc0 * 4) * 256 + kofs0, kb + kc0 * 1024);
        load_lds16(Kgb + (kv0 + (size_t)kc1 * 4) * 256 + kofs1, kb + kc1 * 1024);
    };

    STAGE(0, 0);

    bf16x8 qf[2][2];
    #pragma unroll
    for (int p = 0; p < 2; ++p)
        #pragma unroll
        for (int kc = 0; kc < 2; ++kc)
            qf[p][kc] = *(const bf16x8*)&Qp[(size_t)(qbase + rl) * 128 + p * 64 + kc * 32 + g * 8];

    f32x4 acc[2][4];
    float m[2], l[2];
    #pragma unroll
    for (int p = 0; p < 2; ++p) {
        #pragma unroll
        for (int t = 0; t < 4; ++t) acc[p][t] = (f32x4){0.f, 0.f, 0.f, 0.f};
        m[p] = 0.f; l[p] = 0.f;
    }

    __syncthreads();   // prologue stage drained

    const int NIT = 1024 / 32;
    for (int it = 0; it < NIT; ++it) {
        const int cur = it & 1;
        if (it + 1 < NIT) STAGE(cur ^ 1, it + 1);   // issue-early K prefetch
        const char* kb = Kg0 + cur * 8192;
        const size_t kv0 = (size_t)(kvg * 1024 + it * 32);

        // ---- V fragments straight from global (no in-iter deps -> hoistable) ----
        bf16x8 vf[4];
        #pragma unroll
        for (int t = 0; t < 4; ++t)
            vf[t] = *(const bf16x8*)(Vgb + (size_t)(t * 16 + rl) * 4096 + (kv0 + g * 8) * 2);

        #pragma unroll
        for (int p = 0; p < 2; ++p) {
            // ---- QK^T (swapped: mfma(K,Q)); Q pre-scaled -> exp2 domain ----
            f32x4 sc[2];
            #pragma unroll
            for (int t = 0; t < 2; ++t) {
                f32x4 z = (f32x4){0.f, 0.f, 0.f, 0.f};
                #pragma unroll
                for (int kc = 0; kc < 2; ++kc) {
                    bf16x8 kf = *(const bf16x8*)(kb + t * 4096 + rl * 256 + (((p * 8 + kc * 4 + g) ^ kx) << 4));
                    z = __builtin_amdgcn_mfma_f32_16x16x32_bf16(kf, qf[p][kc], z, 0, 0, 0);
                }
                sc[t] = z;
            }

            // ---- block max per q-row ----
            float mx = fmaxf(fmaxf(fmaxf(sc[0][0], sc[0][1]), fmaxf(sc[0][2], sc[0][3])),
                             fmaxf(fmaxf(sc[1][0], sc[1][1]), fmaxf(sc[1][2], sc[1][3])));
            mx = fmaxf(mx, __shfl_xor(mx, 16, 64));
            mx = fmaxf(mx, __shfl_xor(mx, 32, 64));

            if (it == 0) {
                m[p] = mx;
            } else if (!__all(mx <= m[p] + 8.f)) {
                float mn = fmaxf(m[p], mx);
                float fac = exp2f(m[p] - mn);
                l[p] *= fac; m[p] = mn;
                #pragma unroll
                for (int jj = 0; jj < 4; ++jj) {
                    float fq = __shfl(fac, g * 4 + jj, 64);
                    #pragma unroll
                    for (int t = 0; t < 4; ++t) acc[p][t][jj] *= fq;
                }
            }

            // ---- P = exp2(S - m): packed cvt writes into 128B rows ----
            float rs = 0.f;
            #pragma unroll
            for (int t = 0; t < 2; ++t) {
                #pragma unroll
                for (int jjp = 0; jjp < 4; jjp += 2) {
                    float e0 = exp2f(sc[t][jjp]     - m[p]);
                    float e1 = exp2f(sc[t][jjp + 1] - m[p]);
                    rs += e0 + e1;
                    unsigned u;
                    asm("v_cvt_pk_bf16_f32 %0, %1, %2" : "=v"(u) : "v"(e0), "v"(e1));
                    *(unsigned*)(Pw + rl * 128 + ((p * 64 + (t * 16 + g * 4 + jjp) * 2) ^ swz)) = u;
                }
            }
            rs += __shfl_xor(rs, 16, 64);
            rs += __shfl_xor(rs, 32, 64);
            l[p] += rs;

            // ---- O += P @ V (wave-private P as A; global-loaded V as B; K=32) ----
            bf16x8 pa = *(const bf16x8*)(Pw + rl * 128 + ((p * 64 + g * 16) ^ swz));
            #pragma unroll
            for (int t = 0; t < 4; ++t)
                acc[p][t] = __builtin_amdgcn_mfma_f32_16x16x32_bf16(pa, vf[t], acc[p][t], 0, 0, 0);
        }
        __syncthreads();   // drains this iter's K prefetch; next buffer ready
    }

    // ---- exchange partials through LDS (all staging/P regions dead) ----
    {
        unsigned short* Xw = (unsigned short*)(smem + wave * 4096);  // [2][16][64] bf16
        float* ML = (float*)(smem + 32768);                          // [8w][2p][{m,l}][16]
        #pragma unroll
        for (int p = 0; p < 2; ++p) {
            #pragma unroll
            for (int t = 0; t < 4; ++t)
                #pragma unroll
                for (int jj = 0; jj < 4; ++jj)
                    Xw[p * 1024 + (g * 4 + jj) * 64 + t * 16 + rl] = f2bf(acc[p][t][jj]);
            if (g == 0) {
                ML[(wave * 2 + p) * 32 + rl]      = m[p];
                ML[(wave * 2 + p) * 32 + 16 + rl] = l[p];
            }
        }
    }
    __syncthreads();

    // ---- combine the 2 kv-group partials; thread -> (q = tid>>3, d0 = (tid&7)*8) ----
    {
        const int q = threadIdx.x >> 3, d0 = (threadIdx.x & 7) * 8;
        const int q15 = q & 15, wa = q >> 4, wb = (q >> 4) + 4;
        const float* ML = (const float*)(smem + 32768);
        const float lam = lam_p[0];
        float res[2][8];
        float invL[2];
        #pragma unroll
        for (int p = 0; p < 2; ++p) {
            float ma = ML[(wa * 2 + p) * 32 + q15], la = ML[(wa * 2 + p) * 32 + 16 + q15];
            float mb = ML[(wb * 2 + p) * 32 + q15], lb = ML[(wb * 2 + p) * 32 + 16 + q15];
            float ms = fmaxf(ma, mb);
            float fa = exp2f(ma - ms), fb = exp2f(mb - ms);
            invL[p] = 1.0f / (fa * la + fb * lb);
            const unsigned short* xa = (const unsigned short*)(smem + wa * 4096 + p * 2048 + q15 * 128 + d0 * 2);
            const unsigned short* xb = (const unsigned short*)(smem + wb * 4096 + p * 2048 + q15 * 128 + d0 * 2);
            #pragma unroll
            for (int k = 0; k < 8; ++k)
                res[p][k] = fa * bf2f(xa[k]) + fb * bf2f(xb[k]);
        }
        bf16x8 ov;
        #pragma unroll
        for (int k = 0; k < 8; ++k)
            ov[k] = (short)f2bf(res[0][k] * invL[0] - lam * res[1][k] * invL[1]);
        *(bf16x8*)&Ocat[(size_t)(blockIdx.x * 64 + q) * 1024 + h * 64 + d0] = ov;
    }
}

// ---------------- output projection GEMM (64x128 tiles, LDS-staged) ----------------
__global__ __launch_bounds__(256) void k_gemm_out(
        const short* __restrict__ Ocat, const short* __restrict__ WoT,
        const float* __restrict__ bo, float* __restrict__ Yws) {
    __shared__ __align__(16) char sA[8192], sB[16384];
    int id = blockIdx.x;
    id = (id & 7) * 32 + (id >> 3);
    const int mbase = (id % 32) * 64;
    const int nbase = (id / 32) * 128;

    f32x4 acc[8];
    #pragma unroll
    for (int i = 0; i < 8; ++i) acc[i] = (f32x4){0.f, 0.f, 0.f, 0.f};

    gemm_core<64, 128, 1, 4>((const char*)Ocat + (size_t)mbase * 2048, 2048,
                             (const char*)WoT + (size_t)nbase * 2048, 2048,
                             1024, sA, sB, acc);

    const int lane = threadIdx.x & 63, wave = threadIdx.x >> 6;
    const int rl = lane & 15, g = lane >> 4;
    #pragma unroll
    for (int f = 0; f < 4; ++f)
        #pragma unroll
        for (int j = 0; j < 2; ++j)
            #pragma unroll
            for (int jj = 0; jj < 4; ++jj) {
                int s = mbase + f * 16 + g * 4 + jj;
                int e = nbase + wave * 32 + j * 16 + rl;
                Yws[(size_t)s * 1024 + e] = acc[f * 2 + j][jj] + bo[e];
            }
}

// ---------------- LayerNorm + final scale ----------------
__global__ __launch_bounds__(256) void k_ln(
        const float* __restrict__ Yws, const float* __restrict__ gamma,
        const float* __restrict__ beta, float* __restrict__ out) {
    const int s = blockIdx.x;
    const int tid = threadIdx.x;
    f32x4 y = ((const f32x4*)(Yws + (size_t)s * 1024))[tid];
    float sum = y[0] + y[1] + y[2] + y[3];
    float sq  = y[0]*y[0] + y[1]*y[1] + y[2]*y[2] + y[3]*y[3];
    #pragma unroll
    for (int off = 1; off < 64; off <<= 1) {
        sum += __shfl_xor(sum, off, 64);
        sq  += __shfl_xor(sq,  off, 64);
    }
    __shared__ float ls[2][4];
    const int wave = tid >> 6, lane = tid & 63;
    if (lane == 0) { ls[0][wave] = sum; ls[1][wave] = sq; }
    __syncthreads();
    sum = ls[0][0] + ls[0][1] + ls[0][2] + ls[0][3];
    sq  = ls[1][0] + ls[1][1] + ls[1][2] + ls[1][3];
    const float mu = sum * (1.f / 1024.f);
    const float var = sq * (1.f / 1024.f) - mu * mu;
    const float rstd = rsqrtf(var + 1e-5f);
    f32x4 gg = ((const f32x4*)gamma)[tid];
    f32x4 bb = ((const f32x4*)beta)[tid];
    f32x4 o;
    #pragma unroll
    for (int k = 0; k < 4; ++k)
        o[k] = ((y[k] - mu) * rstd * gg[k] + bb[k]) * 0.2f;
    ((f32x4*)(out + (size_t)s * 1024))[tid] = o;
}

extern "C" void kernel_launch(void* const* d_in, const int* in_sizes, int n_in,
                              void* d_out, int out_size, void* d_ws, size_t ws_size,
                              hipStream_t stream) {
    const float* X     = (const float*)d_in[0];
    const float* Wq    = (const float*)d_in[1];
    const float* bq    = (const float*)d_in[2];
    const float* Wk    = (const float*)d_in[3];
    const float* bk    = (const float*)d_in[4];
    const float* Wv    = (const float*)d_in[5];
    const float* bv    = (const float*)d_in[6];
    const float* Wo    = (const float*)d_in[7];
    const float* bo    = (const float*)d_in[8];
    const float* gamma = (const float*)d_in[9];
    const float* beta  = (const float*)d_in[10];
    const float* lam   = (const float*)d_in[11];
    float* out = (float*)d_out;

    char* ws = (char*)d_ws;
    const size_t MB = 1u << 20;
    short* Xb  = (short*)(ws + 0);        // 4MB (dead after qkv gemm)
    short* WqT = (short*)(ws + 4 * MB);   // 4MB (dead after qkv gemm)
    short* WkT = (short*)(ws + 8 * MB);   // 4MB
    short* WvT = (short*)(ws + 12 * MB);  // 2MB
    short* WoT = (short*)(ws + 14 * MB);  // 2MB
    short* Qh  = (short*)(ws + 16 * MB);  // 8MB
    short* Kh  = (short*)(ws + 24 * MB);  // 8MB
    short* Vt  = (short*)(ws + 32 * MB);  // 4MB
    short* Oc  = (short*)(ws + 36 * MB);  // 4MB
    float* Yws = (float*)(ws + 0);        // 8MB, aliases Xb+WqT (both dead by then)

    k_convert_x<<<dim3(2048), dim3(256), 0, stream>>>(X, Xb, (S_LEN * EDIM) / 4);
    k_transpose_cvt<<<dim3(4, 32, 16), dim3(32, 8), 0, stream>>>(Wq, WqT, 1024, 128);
    k_transpose_cvt<<<dim3(4, 32, 16), dim3(32, 8), 0, stream>>>(Wk, WkT, 1024, 128);
    k_transpose_cvt<<<dim3(2, 32, 16), dim3(32, 8), 0, stream>>>(Wv, WvT, 1024, 64);
    k_transpose_cvt<<<dim3(32, 32, 1), dim3(32, 8), 0, stream>>>(Wo, WoT, 1024, 1024);
    k_gemm_qkv<<<dim3(640), dim3(256), 0, stream>>>(Xb, WqT, WkT, WvT, bq, bk, bv, Qh, Kh, Vt);
    k_attn<<<dim3(32, 16), dim3(512), 0, stream>>>(Qh, Kh, Vt, lam, Oc);
    k_gemm_out<<<dim3(256), dim3(256), 0, stream>>>(Oc, WoT, bo, Yws);
    k_ln<<<dim3(2048), dim3(256), 0, stream>>>(Yws, gamma, beta, out);
}

// Round 12
// 171.876 us; speedup vs baseline: 1.0536x; 1.0238x over previous
//
#include <hip/hip_runtime.h>

#define S_LEN 2048
#define EDIM  1024
#define HEADS 16
#define DHEAD 64

typedef __attribute__((ext_vector_type(8))) short bf16x8;
typedef __attribute__((ext_vector_type(4))) short short4v;
typedef __attribute__((ext_vector_type(4))) float f32x4;

__device__ inline unsigned short f2bf(float f) {
    unsigned int u = __float_as_uint(f);
    unsigned int r = (u + 0x7FFFu + ((u >> 16) & 1u)) >> 16;
    return (unsigned short)r;
}
__device__ inline float bf2f(unsigned short b) {
    return __uint_as_float(((unsigned int)b) << 16);
}
__device__ inline void load_lds16(const void* g, void* l) {
    __builtin_amdgcn_global_load_lds(
        (const __attribute__((address_space(1))) unsigned int*)g,
        (__attribute__((address_space(3))) unsigned int*)l, 16, 0, 0);
}

// ---------------- X fp32 -> bf16 ----------------
__global__ void k_convert_x(const float* __restrict__ x, short* __restrict__ xb, int n4) {
    int i = blockIdx.x * blockDim.x + threadIdx.x;
    if (i >= n4) return;
    f32x4 v = ((const f32x4*)x)[i];
    short4v o;
    o[0] = (short)f2bf(v[0]); o[1] = (short)f2bf(v[1]);
    o[2] = (short)f2bf(v[2]); o[3] = (short)f2bf(v[3]);
    ((short4v*)xb)[i] = o;
}

// ---------------- tiled transpose + fp32->bf16: in[R][C] -> out[C][R], batched over z ----------------
__global__ void k_transpose_cvt(const float* __restrict__ in, short* __restrict__ out, int R, int C) {
    __shared__ float tile[32][33];
    const int b = blockIdx.z;
    in  += (size_t)b * R * C;
    out += (size_t)b * R * C;
    const int c0 = blockIdx.x * 32, r0 = blockIdx.y * 32;
    #pragma unroll
    for (int yy = 0; yy < 4; ++yy) {
        int r = r0 + threadIdx.y + yy * 8, c = c0 + threadIdx.x;
        tile[threadIdx.y + yy * 8][threadIdx.x] = (r < R && c < C) ? in[(size_t)r * C + c] : 0.f;
    }
    __syncthreads();
    #pragma unroll
    for (int yy = 0; yy < 4; ++yy) {
        int c = c0 + threadIdx.y + yy * 8, r = r0 + threadIdx.x;
        if (c < C && r < R) out[(size_t)c * R + r] = (short)f2bf(tile[threadIdx.x][threadIdx.y + yy * 8]);
    }
}

// ---------------- LDS-staged MFMA GEMM core (m97 structure) ----------------
template<int BM, int BN, int WR, int WC>
__device__ inline void gemm_core(const char* Ag, int ldaB, const char* Bg, int ldbB,
                                 int K, char* sA, char* sB, f32x4* acc) {
    constexpr int FM = BM / (WR * 16), FN = BN / (WC * 16);
    constexpr int RA = BM / 32, RB = BN / 32;
    const int lane = threadIdx.x & 63, wave = threadIdx.x >> 6;
    const int rl = lane & 15, g = lane >> 4;
    const int wrow = (wave / WC) * (BM / WR);
    const int wcol = (wave % WC) * (BN / WC);
    const int lr = lane >> 3;                 // row within 8-row staging group
    const int lc = ((lane & 7) ^ lr) << 4;    // inverse-swizzled 16B chunk
    const char* aSrc = Ag + (size_t)(wave * 8 + lr) * ldaB + lc;
    const char* bSrc = Bg + (size_t)(wave * 8 + lr) * ldbB + lc;

    for (int t = 0; t < K / 64; ++t) {
        __syncthreads();
        #pragma unroll
        for (int i = 0; i < RA; ++i)
            load_lds16(aSrc + (size_t)t * 128 + (size_t)i * 32 * ldaB, sA + (i * 4 + wave) * 1024);
        #pragma unroll
        for (int i = 0; i < RB; ++i)
            load_lds16(bSrc + (size_t)t * 128 + (size_t)i * 32 * ldbB, sB + (i * 4 + wave) * 1024);
        __syncthreads();
        #pragma unroll
        for (int kk = 0; kk < 2; ++kk) {
            bf16x8 af[FM], bf[FN];
            #pragma unroll
            for (int f = 0; f < FM; ++f) {
                const int r = wrow + f * 16 + rl;
                af[f] = *(const bf16x8*)(sA + r * 128 + (((kk * 4 + g) ^ (r & 7)) << 4));
            }
            #pragma unroll
            for (int j = 0; j < FN; ++j) {
                const int r = wcol + j * 16 + rl;
                bf[j] = *(const bf16x8*)(sB + r * 128 + (((kk * 4 + g) ^ (r & 7)) << 4));
            }
            #pragma unroll
            for (int f = 0; f < FM; ++f)
                #pragma unroll
                for (int j = 0; j < FN; ++j)
                    acc[f * FN + j] = __builtin_amdgcn_mfma_f32_16x16x32_bf16(af[f], bf[j], acc[f * FN + j], 0, 0, 0);
        }
    }
}

// ---------------- QKV projection GEMM (128x128 tiles, LDS-staged) ----------------
__global__ __launch_bounds__(256) void k_gemm_qkv(
        const short* __restrict__ Xb,
        const short* __restrict__ WqT, const short* __restrict__ WkT, const short* __restrict__ WvT,
        const float* __restrict__ bq, const float* __restrict__ bk, const float* __restrict__ bv,
        short* __restrict__ Qh, short* __restrict__ Kh, short* __restrict__ Vt) {
    __shared__ __align__(16) char sA[16384], sB[16384];
    int id = blockIdx.x;
    id = (id & 7) * 80 + (id >> 3);           // XCD-contiguous chunks
    const int mbase = (id % 16) * 128;
    const int y = id / 16;

    const short* Bt; const float* bias; int nbase; int which;
    if (y < 16)      { which = 0; Bt = WqT; bias = bq; nbase = y * 128; }
    else if (y < 32) { which = 1; Bt = WkT; bias = bk; nbase = (y - 16) * 128; }
    else             { which = 2; Bt = WvT; bias = bv; nbase = (y - 32) * 128; }

    f32x4 acc[16];
    #pragma unroll
    for (int i = 0; i < 16; ++i) acc[i] = (f32x4){0.f, 0.f, 0.f, 0.f};

    gemm_core<128, 128, 2, 2>((const char*)Xb + (size_t)mbase * 2048, 2048,
                              (const char*)Bt + (size_t)nbase * 2048, 2048,
                              EDIM, sA, sB, acc);

    const int lane = threadIdx.x & 63, wave = threadIdx.x >> 6;
    const int wr = (wave >> 1) * 64, wc = (wave & 1) * 64;
    const int rl = lane & 15, g = lane >> 4;
    const float qscale = 0.125f * 1.44269504088896f;
    #pragma unroll
    for (int i = 0; i < 4; ++i)
        #pragma unroll
        for (int j = 0; j < 4; ++j)
            #pragma unroll
            for (int jj = 0; jj < 4; ++jj) {
                int s = mbase + wr + i * 16 + g * 4 + jj;
                int n = nbase + wc + j * 16 + rl;
                float v = acc[i * 4 + j][jj] + bias[n];
                if (which == 0) v *= qscale;
                short b16 = (short)f2bf(v);
                if (which == 0)      Qh[((size_t)(n >> 7) * S_LEN + s) * 128 + (n & 127)] = b16;
                else if (which == 1) Kh[((size_t)(n >> 7) * S_LEN + s) * 128 + (n & 127)] = b16;
                else                 Vt[(size_t)n * S_LEN + s] = b16;
            }
}

// ---------------- differential flash attention, v10: fixed-shift softmax + l via ones-MFMA ----------------
// v9 structure (8 waves, 2-way kv-split, KVBLK=32, dbuf K prefetch, V from
// global, P in 128B-row LDS) with the VALU diet:
//  - softmax shift is a CONSTANT (M=6; scores have sigma~0.6, P/l is a fp
//    ratio so the shift cancels exactly) -> no max tree, no shuffles, no
//    rescale branch, no it==0 special.
//  - row sum l computed by mfma(P, ones) on the idle matrix pipe -> no add
//    chain, no shuffles; l lands in acc layout for the epilogue for free.
__global__ __launch_bounds__(512, 4) void k_attn(
        const short* __restrict__ Qh, const short* __restrict__ Kh,
        const short* __restrict__ Vt, const float* __restrict__ lam_p,
        short* __restrict__ Ocat) {
    __shared__ __align__(16) char smem[49152];

    const int lane = threadIdx.x & 63, wave = threadIdx.x >> 6;
    const int rl = lane & 15, g = lane >> 4;
    const int qw = wave & 3, kvg = wave >> 2;
    const int h = blockIdx.y;
    const int qbase = blockIdx.x * 64 + qw * 16;
    const int kx = rl & 7;              // K-row swizzle key (256B rows)
    const int swz = (rl & 7) << 4;      // P-row swizzle key (128B rows)
    const float MFIX = 6.0f;            // fixed exp2-domain shift (~10 sigma)

    char* Kg0 = smem + kvg * 16384;            // 2 bufs x 8KB: [32 kv][256B]
    char* Pw  = smem + 32768 + wave * 2048;    // [16 q][128B] = {p0 64B | p1 64B} swizzled

    const char* Kgb = (const char*)(Kh + (size_t)h * S_LEN * 128);
    const char* Vgb = (const char*)(Vt + (size_t)h * DHEAD * S_LEN);
    const short* Qp = Qh + (size_t)h * S_LEN * 128;

    // K staging: 8 chunks of 1KB per group per iter; wave qw does chunks {2qw, 2qw+1}
    const int kc0 = qw * 2, kc1 = qw * 2 + 1;
    const int kofs0 = (lane >> 4) * 256 + (((lane & 15) ^ (lane >> 4)) << 4);
    const int kofs1 = (lane >> 4) * 256 + (((lane & 15) ^ ((lane >> 4) + 4)) << 4);

    auto STAGE = [&](int b, int it) {
        const size_t kv0 = (size_t)(kvg * 1024 + it * 32);
        char* kb = Kg0 + b * 8192;
        load_lds16(Kgb + (kv0 + (size_t)kc0 * 4) * 256 + kofs0, kb + kc0 * 1024);
        load_lds16(Kgb + (kv0 + (size_t)kc1 * 4) * 256 + kofs1, kb + kc1 * 1024);
    };

    STAGE(0, 0);

    bf16x8 qf[2][2];
    #pragma unroll
    for (int p = 0; p < 2; ++p)
        #pragma unroll
        for (int kc = 0; kc < 2; ++kc)
            qf[p][kc] = *(const bf16x8*)&Qp[(size_t)(qbase + rl) * 128 + p * 64 + kc * 32 + g * 8];

    bf16x8 ones;
    #pragma unroll
    for (int i = 0; i < 8; ++i) ones[i] = (short)0x3F80;   // bf16 1.0

    f32x4 acc[2][4], accL[2];
    #pragma unroll
    for (int p = 0; p < 2; ++p) {
        #pragma unroll
        for (int t = 0; t < 4; ++t) acc[p][t] = (f32x4){0.f, 0.f, 0.f, 0.f};
        accL[p] = (f32x4){0.f, 0.f, 0.f, 0.f};
    }

    __syncthreads();   // prologue stage drained

    const int NIT = 1024 / 32;
    for (int it = 0; it < NIT; ++it) {
        const int cur = it & 1;
        if (it + 1 < NIT) STAGE(cur ^ 1, it + 1);   // issue-early K prefetch
        const char* kb = Kg0 + cur * 8192;
        const size_t kv0 = (size_t)(kvg * 1024 + it * 32);

        // ---- V fragments straight from global (no in-iter deps -> hoistable) ----
        bf16x8 vf[4];
        #pragma unroll
        for (int t = 0; t < 4; ++t)
            vf[t] = *(const bf16x8*)(Vgb + (size_t)(t * 16 + rl) * 4096 + (kv0 + g * 8) * 2);

        #pragma unroll
        for (int p = 0; p < 2; ++p) {
            // ---- QK^T (swapped: mfma(K,Q)); Q pre-scaled -> exp2 domain ----
            f32x4 sc[2];
            #pragma unroll
            for (int t = 0; t < 2; ++t) {
                f32x4 z = (f32x4){0.f, 0.f, 0.f, 0.f};
                #pragma unroll
                for (int kc = 0; kc < 2; ++kc) {
                    bf16x8 kf = *(const bf16x8*)(kb + t * 4096 + rl * 256 + (((p * 8 + kc * 4 + g) ^ kx) << 4));
                    z = __builtin_amdgcn_mfma_f32_16x16x32_bf16(kf, qf[p][kc], z, 0, 0, 0);
                }
                sc[t] = z;
            }

            // ---- P = exp2(S - MFIX): packed cvt writes into 128B rows ----
            #pragma unroll
            for (int t = 0; t < 2; ++t) {
                #pragma unroll
                for (int jjp = 0; jjp < 4; jjp += 2) {
                    float e0 = exp2f(sc[t][jjp]     - MFIX);
                    float e1 = exp2f(sc[t][jjp + 1] - MFIX);
                    unsigned u;
                    asm("v_cvt_pk_bf16_f32 %0, %1, %2" : "=v"(u) : "v"(e0), "v"(e1));
                    *(unsigned*)(Pw + rl * 128 + ((p * 64 + (t * 16 + g * 4 + jjp) * 2) ^ swz)) = u;
                }
            }

            // ---- O += P @ V; l += P @ ones (row sums on the matrix pipe) ----
            bf16x8 pa = *(const bf16x8*)(Pw + rl * 128 + ((p * 64 + g * 16) ^ swz));
            accL[p] = __builtin_amdgcn_mfma_f32_16x16x32_bf16(pa, ones, accL[p], 0, 0, 0);
            #pragma unroll
            for (int t = 0; t < 4; ++t)
                acc[p][t] = __builtin_amdgcn_mfma_f32_16x16x32_bf16(pa, vf[t], acc[p][t], 0, 0, 0);
        }
        __syncthreads();   // drains this iter's K prefetch; next buffer ready
    }

    // ---- exchange partials through LDS (all staging/P regions dead) ----
    {
        unsigned short* Xw = (unsigned short*)(smem + wave * 4096);  // [2][16][64] bf16
        float* ML = (float*)(smem + 32768);                          // [8w][2p][16 q] l only
        #pragma unroll
        for (int p = 0; p < 2; ++p) {
            #pragma unroll
            for (int t = 0; t < 4; ++t)
                #pragma unroll
                for (int jj = 0; jj < 4; ++jj)
                    Xw[p * 1024 + (g * 4 + jj) * 64 + t * 16 + rl] = f2bf(acc[p][t][jj]);
            if (rl == 0) {
                #pragma unroll
                for (int jj = 0; jj < 4; ++jj)
                    ML[(wave * 2 + p) * 16 + g * 4 + jj] = accL[p][jj];
            }
        }
    }
    __syncthreads();

    // ---- combine the 2 kv-group partials; thread -> (q = tid>>3, d0 = (tid&7)*8) ----
    {
        const int q = threadIdx.x >> 3, d0 = (threadIdx.x & 7) * 8;
        const int q15 = q & 15, wa = q >> 4, wb = (q >> 4) + 4;
        const float* ML = (const float*)(smem + 32768);
        const float lam = lam_p[0];
        float res[2][8];
        float invL[2];
        #pragma unroll
        for (int p = 0; p < 2; ++p) {
            float la = ML[(wa * 2 + p) * 16 + q15];
            float lb = ML[(wb * 2 + p) * 16 + q15];
            invL[p] = 1.0f / (la + lb);
            const unsigned short* xa = (const unsigned short*)(smem + wa * 4096 + p * 2048 + q15 * 128 + d0 * 2);
            const unsigned short* xb = (const unsigned short*)(smem + wb * 4096 + p * 2048 + q15 * 128 + d0 * 2);
            #pragma unroll
            for (int k = 0; k < 8; ++k)
                res[p][k] = bf2f(xa[k]) + bf2f(xb[k]);
        }
        bf16x8 ov;
        #pragma unroll
        for (int k = 0; k < 8; ++k)
            ov[k] = (short)f2bf(res[0][k] * invL[0] - lam * res[1][k] * invL[1]);
        *(bf16x8*)&Ocat[(size_t)(blockIdx.x * 64 + q) * 1024 + h * 64 + d0] = ov;
    }
}

// ---------------- output projection GEMM (64x128 tiles, LDS-staged) ----------------
__global__ __launch_bounds__(256) void k_gemm_out(
        const short* __restrict__ Ocat, const short* __restrict__ WoT,
        const float* __restrict__ bo, float* __restrict__ Yws) {
    __shared__ __align__(16) char sA[8192], sB[16384];
    int id = blockIdx.x;
    id = (id & 7) * 32 + (id >> 3);
    const int mbase = (id % 32) * 64;
    const int nbase = (id / 32) * 128;

    f32x4 acc[8];
    #pragma unroll
    for (int i = 0; i < 8; ++i) acc[i] = (f32x4){0.f, 0.f, 0.f, 0.f};

    gemm_core<64, 128, 1, 4>((const char*)Ocat + (size_t)mbase * 2048, 2048,
                             (const char*)WoT + (size_t)nbase * 2048, 2048,
                             1024, sA, sB, acc);

    const int lane = threadIdx.x & 63, wave = threadIdx.x >> 6;
    const int rl = lane & 15, g = lane >> 4;
    #pragma unroll
    for (int f = 0; f < 4; ++f)
        #pragma unroll
        for (int j = 0; j < 2; ++j)
            #pragma unroll
            for (int jj = 0; jj < 4; ++jj) {
                int s = mbase + f * 16 + g * 4 + jj;
                int e = nbase + wave * 32 + j * 16 + rl;
                Yws[(size_t)s * 1024 + e] = acc[f * 2 + j][jj] + bo[e];
            }
}

// ---------------- LayerNorm + final scale ----------------
__global__ __launch_bounds__(256) void k_ln(
        const float* __restrict__ Yws, const float* __restrict__ gamma,
        const float* __restrict__ beta, float* __restrict__ out) {
    const int s = blockIdx.x;
    const int tid = threadIdx.x;
    f32x4 y = ((const f32x4*)(Yws + (size_t)s * 1024))[tid];
    float sum = y[0] + y[1] + y[2] + y[3];
    float sq  = y[0]*y[0] + y[1]*y[1] + y[2]*y[2] + y[3]*y[3];
    #pragma unroll
    for (int off = 1; off < 64; off <<= 1) {
        sum += __shfl_xor(sum, off, 64);
        sq  += __shfl_xor(sq,  off, 64);
    }
    __shared__ float ls[2][4];
    const int wave = tid >> 6, lane = tid & 63;
    if (lane == 0) { ls[0][wave] = sum; ls[1][wave] = sq; }
    __syncthreads();
    sum = ls[0][0] + ls[0][1] + ls[0][2] + ls[0][3];
    sq  = ls[1][0] + ls[1][1] + ls[1][2] + ls[1][3];
    const float mu = sum * (1.f / 1024.f);
    const float var = sq * (1.f / 1024.f) - mu * mu;
    const float rstd = rsqrtf(var + 1e-5f);
    f32x4 gg = ((const f32x4*)gamma)[tid];
    f32x4 bb = ((const f32x4*)beta)[tid];
    f32x4 o;
    #pragma unroll
    for (int k = 0; k < 4; ++k)
        o[k] = ((y[k] - mu) * rstd * gg[k] + bb[k]) * 0.2f;
    ((f32x4*)(out + (size_t)s * 1024))[tid] = o;
}

extern "C" void kernel_launch(void* const* d_in, const int* in_sizes, int n_in,
                              void* d_out, int out_size, void* d_ws, size_t ws_size,
                              hipStream_t stream) {
    const float* X     = (const float*)d_in[0];
    const float* Wq    = (const float*)d_in[1];
    const float* bq    = (const float*)d_in[2];
    const float* Wk    = (const float*)d_in[3];
    const float* bk    = (const float*)d_in[4];
    const float* Wv    = (const float*)d_in[5];
    const float* bv    = (const float*)d_in[6];
    const float* Wo    = (const float*)d_in[7];
    const float* bo    = (const float*)d_in[8];
    const float* gamma = (const float*)d_in[9];
    const float* beta  = (const float*)d_in[10];
    const float* lam   = (const float*)d_in[11];
    float* out = (float*)d_out;

    char* ws = (char*)d_ws;
    const size_t MB = 1u << 20;
    short* Xb  = (short*)(ws + 0);        // 4MB (dead after qkv gemm)
    short* WqT = (short*)(ws + 4 * MB);   // 4MB (dead after qkv gemm)
    short* WkT = (short*)(ws + 8 * MB);   // 4MB
    short* WvT = (short*)(ws + 12 * MB);  // 2MB
    short* WoT = (short*)(ws + 14 * MB);  // 2MB
    short* Qh  = (short*)(ws + 16 * MB);  // 8MB
    short* Kh  = (short*)(ws + 24 * MB);  // 8MB
    short* Vt  = (short*)(ws + 32 * MB);  // 4MB
    short* Oc  = (short*)(ws + 36 * MB);  // 4MB
    float* Yws = (float*)(ws + 0);        // 8MB, aliases Xb+WqT (both dead by then)

    k_convert_x<<<dim3(2048), dim3(256), 0, stream>>>(X, Xb, (S_LEN * EDIM) / 4);
    k_transpose_cvt<<<dim3(4, 32, 16), dim3(32, 8), 0, stream>>>(Wq, WqT, 1024, 128);
    k_transpose_cvt<<<dim3(4, 32, 16), dim3(32, 8), 0, stream>>>(Wk, WkT, 1024, 128);
    k_transpose_cvt<<<dim3(2, 32, 16), dim3(32, 8), 0, stream>>>(Wv, WvT, 1024, 64);
    k_transpose_cvt<<<dim3(32, 32, 1), dim3(32, 8), 0, stream>>>(Wo, WoT, 1024, 1024);
    k_gemm_qkv<<<dim3(640), dim3(256), 0, stream>>>(Xb, WqT, WkT, WvT, bq, bk, bv, Qh, Kh, Vt);
    k_attn<<<dim3(32, 16), dim3(512), 0, stream>>>(Qh, Kh, Vt, lam, Oc);
    k_gemm_out<<<dim3(256), dim3(256), 0, stream>>>(Oc, WoT, bo, Yws);
    k_ln<<<dim3(2048), dim3(256), 0, stream>>>(Yws, gamma, beta, out);
}